// Round 2
// baseline (1442.255 us; speedup 1.0000x reference)
//
#include <hip/hip_runtime.h>
#include <stdint.h>

typedef __attribute__((ext_vector_type(8))) short bf16x8;
typedef __attribute__((ext_vector_type(4))) float f32x4;

__device__ __forceinline__ unsigned short f2bf(float f) {
  unsigned u = __float_as_uint(f);
  u += 0x7FFFu + ((u >> 16) & 1u);
  return (unsigned short)(u >> 16);
}
__device__ __forceinline__ float bf2f(unsigned short b) {
  return __uint_as_float(((unsigned)b) << 16);
}
// monotone float->u32 transform (order-preserving), and inverse
__device__ __forceinline__ unsigned xform(float s) {
  unsigned u = __float_as_uint(s);
  return (u & 0x80000000u) ? ~u : (u | 0x80000000u);
}
__device__ __forceinline__ float inv_xform(unsigned t) {
  unsigned u = (t & 0x80000000u) ? (t & 0x7FFFFFFFu) : ~t;
  return __uint_as_float(u);
}

__device__ __forceinline__ void gl_lds16(const void* g, void* l) {
  __builtin_amdgcn_global_load_lds(
      (const __attribute__((address_space(1))) unsigned*)g,
      (__attribute__((address_space(3))) unsigned*)l, 16, 0, 0);
}

// ---------------- mem fp32 -> bf16 ----------------
__global__ void kcvt(const float* __restrict__ a, unsigned short* __restrict__ o, int n) {
  int i = blockIdx.x * 256 + threadIdx.x;
  if (i < n) o[i] = f2bf(a[i]);
}

// ---------------- per-pixel 1/||feat|| ----------------
// q = feat/||feat|| (mask scaling is uniform over channels, cancels in l2norm)
__global__ void knorm(const float* __restrict__ feat, float* __restrict__ rnorm) {
  int base = blockIdx.x * 64;
  int lane = threadIdx.x & 63, w = threadIdx.x >> 6;
  int n = base + lane;
  int b = n >> 12, hw = n & 4095;
  const float* fp = feat + (size_t)b * (512 * 4096) + hw;
  float s = 0.f;
  #pragma unroll 4
  for (int c = w * 128; c < w * 128 + 128; ++c) {
    float v = fp[(size_t)c * 4096];
    s += v * v;
  }
  __shared__ float red[4][64];
  red[w][lane] = s;
  __syncthreads();
  if (w == 0) {
    float t = red[0][lane] + red[1][lane] + red[2][lane] + red[3][lane];
    rnorm[n] = 1.0f / fmaxf(sqrtf(t), 1e-12f);
  }
}

// ---------------- qf (bf16, [N,512]) + fp32 q output channels ----------------
__global__ void kqf(const float* __restrict__ feat, const float* __restrict__ rnorm,
                    unsigned short* __restrict__ qf, float* __restrict__ out) {
  int c0 = blockIdx.x * 64, n0 = blockIdx.y * 64;
  int lane = threadIdx.x & 63, ty = threadIdx.x >> 6;
  int b = n0 >> 12, hw0 = n0 & 4095;
  __shared__ float tile[64][65];
  float rn = rnorm[n0 + lane];
  const float* fp = feat + (size_t)b * (512 * 4096) + hw0 + lane;
  #pragma unroll
  for (int i = 0; i < 16; ++i) {
    int c = ty * 16 + i;
    float q = fp[(size_t)(c0 + c) * 4096] * rn;
    tile[c][lane] = q;
    size_t obase = ((size_t)b * 2048 + (c0 + c)) * 4096 + hw0 + lane;
    out[obase] = q;                        // channels [0,512)    (real-branch q)
    out[obase + (size_t)1024 * 4096] = q;  // channels [1024,1536) (fake-branch q)
  }
  __syncthreads();
  #pragma unroll
  for (int i = 0; i < 16; ++i) {
    int nn = ty * 16 + i;
    qf[(size_t)(n0 + nn) * 512 + c0 + lane] = f2bf(tile[lane][nn]);
  }
}

// ---------------- GEMM (A[*,K] x B[*,K]^T), 128x128 tile, fused epilogues ----
// MODE 0: score pass  -> rowPack (u64 max: score|col) + colMax (u32 max)
// MODE 1: read pass   -> E = exp(score2) bf16 + rowsum atomics
// MODE 2: PV pass     -> out = (E @ muT)/rowsum, fp32 transposed store to d_out
template <int MODE>
__global__ __launch_bounds__(256) void gemm128(
    const unsigned short* __restrict__ A, const unsigned short* __restrict__ B,
    int K, int ldE,
    unsigned long long* __restrict__ rowPack, unsigned* __restrict__ colMax,
    unsigned short* __restrict__ Eout, float* __restrict__ rowsum,
    float* __restrict__ out, const float* __restrict__ rsin, int chBase) {
  __shared__ __align__(16) unsigned char smraw[33792];
  unsigned short* As = (unsigned short*)smraw;
  unsigned short* Bs = As + 8192;
  const int m0 = blockIdx.x * 128;
  const int n0 = blockIdx.y * 128;
  const int tid = threadIdx.x;
  const int wid = tid >> 6, lane = tid & 63;
  const int wr = wid >> 1, wc = wid & 1;
  const int lr = lane & 15, lg = lane >> 4;
  const int srow = lane >> 3, scol = (lane & 7) * 8;

  f32x4 acc[4][4];
  #pragma unroll
  for (int i = 0; i < 4; ++i)
    #pragma unroll
    for (int j = 0; j < 4; ++j) acc[i][j] = (f32x4){0.f, 0.f, 0.f, 0.f};

  for (int k0 = 0; k0 < K; k0 += 64) {
    __syncthreads();
    #pragma unroll
    for (int i = 0; i < 4; ++i) {
      int ci = wid * 4 + i;
      int row = ci * 8 + srow;
      gl_lds16(A + (size_t)(n0 + row) * K + k0 + scol, As + ci * 512);
      gl_lds16(B + (size_t)(m0 + row) * K + k0 + scol, Bs + ci * 512);
    }
    __syncthreads();
    #pragma unroll
    for (int kk = 0; kk < 64; kk += 32) {
      bf16x8 af[4], bfr[4];
      #pragma unroll
      for (int f = 0; f < 4; ++f)
        af[f] = *(const bf16x8*)&As[(wr * 64 + f * 16 + lr) * 64 + kk + lg * 8];
      #pragma unroll
      for (int f = 0; f < 4; ++f)
        bfr[f] = *(const bf16x8*)&Bs[(wc * 64 + f * 16 + lr) * 64 + kk + lg * 8];
      #pragma unroll
      for (int fi = 0; fi < 4; ++fi)
        #pragma unroll
        for (int fj = 0; fj < 4; ++fj)
          acc[fi][fj] = __builtin_amdgcn_mfma_f32_16x16x32_bf16(af[fi], bfr[fj], acc[fi][fj], 0, 0, 0);
    }
  }
  // D frag mapping (verified m89): col = lr (+fj*16), row = lg*4+r (+fi*16)

  if constexpr (MODE == 0) {
    #pragma unroll
    for (int fi = 0; fi < 4; ++fi) {
      #pragma unroll
      for (int r = 0; r < 4; ++r) {
        float best = acc[fi][0][r];
        int bj = 0;
        #pragma unroll
        for (int fj = 1; fj < 4; ++fj) {
          float v = acc[fi][fj][r];
          if (v > best) { best = v; bj = fj; }
        }
        int col = m0 + wc * 64 + bj * 16 + lr;
        unsigned long long pk =
            ((unsigned long long)xform(best) << 32) | (unsigned)(0xFFFFFFFFu - (unsigned)col);
        #pragma unroll
        for (int msk = 1; msk < 16; msk <<= 1) {
          unsigned long long o = __shfl_xor(pk, msk);
          if (o > pk) pk = o;
        }
        if (lr == 0) atomicMax(&rowPack[n0 + wr * 64 + fi * 16 + lg * 4 + r], pk);
      }
    }
    #pragma unroll
    for (int fj = 0; fj < 4; ++fj) {
      float cm = acc[0][fj][0];
      #pragma unroll
      for (int fi = 0; fi < 4; ++fi)
        #pragma unroll
        for (int r = 0; r < 4; ++r) cm = fmaxf(cm, acc[fi][fj][r]);
      cm = fmaxf(cm, __shfl_xor(cm, 16));
      cm = fmaxf(cm, __shfl_xor(cm, 32));
      if (lg == 0) atomicMax(&colMax[m0 + wc * 64 + fj * 16 + lr], xform(cm));
    }
  }

  if constexpr (MODE == 1) {
    __syncthreads();
    unsigned short(*bt)[130] = (unsigned short(*)[130])smraw;
    #pragma unroll
    for (int fi = 0; fi < 4; ++fi) {
      #pragma unroll
      for (int r = 0; r < 4; ++r) {
        int rowl = wr * 64 + fi * 16 + lg * 4 + r;
        float p = 0.f;
        #pragma unroll
        for (int fj = 0; fj < 4; ++fj) {
          float e = __expf(acc[fi][fj][r]);
          p += e;
          bt[rowl][wc * 64 + fj * 16 + lr] = f2bf(e);
        }
        #pragma unroll
        for (int msk = 1; msk < 16; msk <<= 1) p += __shfl_xor(p, msk);
        if (lr == 0) atomicAdd(&rowsum[n0 + rowl], p);
      }
    }
    __syncthreads();
    int row = tid >> 1, half = tid & 1;
    unsigned short* dst = Eout + (size_t)(n0 + row) * ldE + m0 + half * 64;
    const unsigned* su = (const unsigned*)(bt[row] + half * 64);
    #pragma unroll
    for (int i = 0; i < 8; ++i) {
      uint4 q4 = make_uint4(su[i * 4 + 0], su[i * 4 + 1], su[i * 4 + 2], su[i * 4 + 3]);
      *(uint4*)(dst + i * 8) = q4;
    }
  }

  if constexpr (MODE == 2) {
    float(*bt32)[132] = (float(*)[132])smraw;
    const int b = n0 >> 12, hw0 = n0 & 4095;
    #pragma unroll
    for (int h = 0; h < 2; ++h) {
      __syncthreads();
      if (wc == h) {
        #pragma unroll
        for (int fi = 0; fi < 4; ++fi) {
          #pragma unroll
          for (int r = 0; r < 4; ++r) {
            int rowl = wr * 64 + fi * 16 + lg * 4 + r;
            float inv = 1.0f / rsin[n0 + rowl];
            #pragma unroll
            for (int fj = 0; fj < 4; ++fj)
              bt32[fj * 16 + lr][rowl] = acc[fi][fj][r] * inv;
          }
        }
      }
      __syncthreads();
      float* ob = out + ((size_t)b * 2048 + chBase + m0 + h * 64) * 4096 + hw0;
      #pragma unroll
      for (int t = 0; t < 8; ++t) {
        int idx = t * 256 + tid;
        int row = idx >> 5;        // channel within this 64-half
        int off = (idx & 31) * 4;  // pixel offset, float4
        *(float4*)&ob[(size_t)row * 4096 + off] = *(const float4*)&bt32[row][off];
      }
    }
  }
}

// ---------------- scatter: q_update[gi] += w * qf[n] ----------------
__global__ void kscatter(const unsigned short* __restrict__ qf,
                         const unsigned long long* __restrict__ rowPack,
                         const unsigned* __restrict__ colMax,
                         float* __restrict__ q_update) {
  int n = blockIdx.x * 4 + (threadIdx.x >> 6);
  int lane = threadIdx.x & 63;
  unsigned long long pk = rowPack[n];
  float smax = inv_xform((unsigned)(pk >> 32));
  int col = (int)(0xFFFFFFFFu - (unsigned)(pk & 0xFFFFFFFFu));
  float w = __expf(smax - inv_xform(colMax[col]));
  const uint4 v = *(const uint4*)(qf + (size_t)n * 512 + lane * 8);
  float* dst = q_update + (size_t)col * 512 + lane * 8;
  const unsigned* pv = (const unsigned*)&v;
  #pragma unroll
  for (int i = 0; i < 4; ++i) {
    atomicAdd(dst + 2 * i, w * bf2f((unsigned short)(pv[i] & 0xFFFF)));
    atomicAdd(dst + 2 * i + 1, w * bf2f((unsigned short)(pv[i] >> 16)));
  }
}

// ---------------- mem_upd = l2norm(q_update + mem), also transposed copy ----
__global__ void kmemupd(const float* __restrict__ q_update, const float* __restrict__ mem,
                        unsigned short* __restrict__ mu, unsigned short* __restrict__ muT) {
  int row = blockIdx.x * 4 + (threadIdx.x >> 6);
  int lane = threadIdx.x & 63;
  float v[8];
  float ss = 0.f;
  #pragma unroll
  for (int e = 0; e < 8; ++e) {
    int c = e * 64 + lane;
    float t = q_update[(size_t)row * 512 + c] + mem[(size_t)row * 512 + c];
    v[e] = t;
    ss += t * t;
  }
  #pragma unroll
  for (int m = 1; m < 64; m <<= 1) ss += __shfl_xor(ss, m);
  float rn = 1.0f / fmaxf(sqrtf(ss), 1e-12f);
  #pragma unroll
  for (int e = 0; e < 8; ++e) {
    int c = e * 64 + lane;
    unsigned short bb = f2bf(v[e] * rn);
    mu[(size_t)row * 512 + c] = bb;
    muT[(size_t)c * 1024 + row] = bb;
  }
}

extern "C" void kernel_launch(void* const* d_in, const int* in_sizes, int n_in,
                              void* d_out, int out_size, void* d_ws, size_t ws_size,
                              hipStream_t stream) {
  const float* feat = (const float*)d_in[0];
  const float* memR = (const float*)d_in[2];
  const float* memF = (const float*)d_in[3];
  float* out = (float*)d_out;
  char* ws = (char*)d_ws;

  size_t off = 0;
  auto alloc = [&](size_t bytes) {
    void* p = ws + off;
    off += (bytes + 255) & ~(size_t)255;
    return p;
  };
  unsigned short* qf = (unsigned short*)alloc(33554432);   // [32768,512] bf16
  unsigned short* E = (unsigned short*)alloc(67108864);    // [32768,1024] bf16
  float* q_update = (float*)alloc(2097152);                // [1024,512] f32  (zeroed)
  unsigned long long* rowPack = (unsigned long long*)alloc(262144);  // (zeroed)
  unsigned* colMax = (unsigned*)alloc(4096);               // (zeroed)
  float* rowsum = (float*)alloc(131072);                   // (zeroed)
  size_t zero_bytes = ((char*)rowsum + 131072) - (char*)q_update;
  unsigned short* mu = (unsigned short*)alloc(1048576);    // [1024,512] bf16
  unsigned short* muT = (unsigned short*)alloc(1048576);   // [512,1024] bf16
  unsigned short* memRb = (unsigned short*)alloc(1048576);
  unsigned short* memFb = (unsigned short*)alloc(1048576);
  float* rnorm = (float*)alloc(131072);
  if (off > ws_size) return;  // workspace too small: fail validation cleanly

  kcvt<<<2048, 256, 0, stream>>>(memR, memRb, 524288);
  kcvt<<<2048, 256, 0, stream>>>(memF, memFb, 524288);
  knorm<<<512, 256, 0, stream>>>(feat, rnorm);
  kqf<<<dim3(8, 512), 256, 0, stream>>>(feat, rnorm, qf, out);

  for (int br = 0; br < 2; ++br) {
    const unsigned short* mb = br ? memFb : memRb;
    const float* mf = br ? memF : memR;
    int chBase = 512 + br * 1024;
    hipMemsetAsync(q_update, 0, zero_bytes, stream);
    gemm128<0><<<dim3(8, 256), 256, 0, stream>>>(qf, mb, 512, 0, rowPack, colMax,
                                                 nullptr, nullptr, nullptr, nullptr, 0);
    kscatter<<<8192, 256, 0, stream>>>(qf, rowPack, colMax, q_update);
    kmemupd<<<256, 256, 0, stream>>>(q_update, mf, mu, muT);
    gemm128<1><<<dim3(8, 256), 256, 0, stream>>>(qf, mu, 512, 1024, nullptr, nullptr,
                                                 E, rowsum, nullptr, nullptr, 0);
    gemm128<2><<<dim3(4, 256), 256, 0, stream>>>(E, muT, 1024, 0, nullptr, nullptr,
                                                 nullptr, nullptr, out, rowsum, chBase);
  }
}

// Round 3
// 575.524 us; speedup vs baseline: 2.5060x; 2.5060x over previous
//
#include <hip/hip_runtime.h>
#include <stdint.h>

typedef __attribute__((ext_vector_type(8))) short bf16x8;
typedef __attribute__((ext_vector_type(4))) float f32x4;

__device__ __forceinline__ unsigned short f2bf(float f) {
  unsigned u = __float_as_uint(f);
  u += 0x7FFFu + ((u >> 16) & 1u);
  return (unsigned short)(u >> 16);
}
__device__ __forceinline__ float bf2f(unsigned short b) {
  return __uint_as_float(((unsigned)b) << 16);
}
// monotone float->u32 transform (order-preserving), and inverse
__device__ __forceinline__ unsigned xform(float s) {
  unsigned u = __float_as_uint(s);
  return (u & 0x80000000u) ? ~u : (u | 0x80000000u);
}
__device__ __forceinline__ float inv_xform(unsigned t) {
  unsigned u = (t & 0x80000000u) ? (t & 0x7FFFFFFFu) : ~t;
  return __uint_as_float(u);
}

__device__ __forceinline__ void gl_lds16(const void* g, void* l) {
  __builtin_amdgcn_global_load_lds(
      (const __attribute__((address_space(1))) unsigned*)g,
      (__attribute__((address_space(3))) unsigned*)l, 16, 0, 0);
}

// ---------------- mem fp32 -> bf16 ----------------
__global__ void kcvt(const float* __restrict__ a, unsigned short* __restrict__ o, int n) {
  int i = blockIdx.x * 256 + threadIdx.x;
  if (i < n) o[i] = f2bf(a[i]);
}

// ---------------- per-pixel 1/||feat|| ----------------
// q = feat/||feat|| (mask scaling is uniform over channels, cancels in l2norm)
__global__ void knorm(const float* __restrict__ feat, float* __restrict__ rnorm) {
  int base = blockIdx.x * 64;
  int lane = threadIdx.x & 63, w = threadIdx.x >> 6;
  int n = base + lane;
  int b = n >> 12, hw = n & 4095;
  const float* fp = feat + (size_t)b * (512 * 4096) + hw;
  float s = 0.f;
  #pragma unroll 4
  for (int c = w * 128; c < w * 128 + 128; ++c) {
    float v = fp[(size_t)c * 4096];
    s += v * v;
  }
  __shared__ float red[4][64];
  red[w][lane] = s;
  __syncthreads();
  if (w == 0) {
    float t = red[0][lane] + red[1][lane] + red[2][lane] + red[3][lane];
    rnorm[n] = 1.0f / fmaxf(sqrtf(t), 1e-12f);
  }
}

// ---------------- qf (bf16, [N,512]) + fp32 q output channels ----------------
__global__ void kqf(const float* __restrict__ feat, const float* __restrict__ rnorm,
                    unsigned short* __restrict__ qf, float* __restrict__ out) {
  int c0 = blockIdx.x * 64, n0 = blockIdx.y * 64;
  int lane = threadIdx.x & 63, ty = threadIdx.x >> 6;
  int b = n0 >> 12, hw0 = n0 & 4095;
  __shared__ float tile[64][65];
  float rn = rnorm[n0 + lane];
  const float* fp = feat + (size_t)b * (512 * 4096) + hw0 + lane;
  #pragma unroll
  for (int i = 0; i < 16; ++i) {
    int c = ty * 16 + i;
    float q = fp[(size_t)(c0 + c) * 4096] * rn;
    tile[c][lane] = q;
    size_t obase = ((size_t)b * 2048 + (c0 + c)) * 4096 + hw0 + lane;
    out[obase] = q;                        // channels [0,512)    (real-branch q)
    out[obase + (size_t)1024 * 4096] = q;  // channels [1024,1536) (fake-branch q)
  }
  __syncthreads();
  #pragma unroll
  for (int i = 0; i < 16; ++i) {
    int nn = ty * 16 + i;
    qf[(size_t)(n0 + nn) * 512 + c0 + lane] = f2bf(tile[lane][nn]);
  }
}

// ---------------- GEMM (A[*,K] x B[*,K]^T), 128x128 tile, fused epilogues ----
// MODE 0: score pass  -> rowPack (u64 max: score|col) + colMax (u32 max)
// MODE 1: read pass   -> E = exp(score2) bf16 + rowsum atomics
// MODE 2: PV pass     -> out = (E @ muT)/rowsum, fp32 transposed store to d_out
template <int MODE>
__global__ __launch_bounds__(256) void gemm128(
    const unsigned short* __restrict__ A, const unsigned short* __restrict__ B,
    int K, int ldE,
    unsigned long long* __restrict__ rowPack, unsigned* __restrict__ colMax,
    unsigned short* __restrict__ Eout, float* __restrict__ rowsum,
    float* __restrict__ out, const float* __restrict__ rsin, int chBase) {
  __shared__ __align__(16) unsigned char smraw[33792];
  unsigned short* As = (unsigned short*)smraw;
  unsigned short* Bs = As + 8192;
  const int m0 = blockIdx.x * 128;
  const int n0 = blockIdx.y * 128;
  const int tid = threadIdx.x;
  const int wid = tid >> 6, lane = tid & 63;
  const int wr = wid >> 1, wc = wid & 1;
  const int lr = lane & 15, lg = lane >> 4;
  const int srow = lane >> 3, scol = (lane & 7) * 8;

  f32x4 acc[4][4];
  #pragma unroll
  for (int i = 0; i < 4; ++i)
    #pragma unroll
    for (int j = 0; j < 4; ++j) acc[i][j] = (f32x4){0.f, 0.f, 0.f, 0.f};

  for (int k0 = 0; k0 < K; k0 += 64) {
    __syncthreads();
    #pragma unroll
    for (int i = 0; i < 4; ++i) {
      int ci = wid * 4 + i;
      int row = ci * 8 + srow;
      gl_lds16(A + (size_t)(n0 + row) * K + k0 + scol, As + ci * 512);
      gl_lds16(B + (size_t)(m0 + row) * K + k0 + scol, Bs + ci * 512);
    }
    __syncthreads();
    #pragma unroll
    for (int kk = 0; kk < 64; kk += 32) {
      bf16x8 af[4], bfr[4];
      #pragma unroll
      for (int f = 0; f < 4; ++f)
        af[f] = *(const bf16x8*)&As[(wr * 64 + f * 16 + lr) * 64 + kk + lg * 8];
      #pragma unroll
      for (int f = 0; f < 4; ++f)
        bfr[f] = *(const bf16x8*)&Bs[(wc * 64 + f * 16 + lr) * 64 + kk + lg * 8];
      #pragma unroll
      for (int fi = 0; fi < 4; ++fi)
        #pragma unroll
        for (int fj = 0; fj < 4; ++fj)
          acc[fi][fj] = __builtin_amdgcn_mfma_f32_16x16x32_bf16(af[fi], bfr[fj], acc[fi][fj], 0, 0, 0);
    }
  }
  // D frag mapping (verified m89): col = lr (+fj*16), row = lg*4+r (+fi*16)

  if constexpr (MODE == 0) {
    #pragma unroll
    for (int fi = 0; fi < 4; ++fi) {
      #pragma unroll
      for (int r = 0; r < 4; ++r) {
        float best = acc[fi][0][r];
        int bj = 0;
        #pragma unroll
        for (int fj = 1; fj < 4; ++fj) {
          float v = acc[fi][fj][r];
          if (v > best) { best = v; bj = fj; }
        }
        int col = m0 + wc * 64 + bj * 16 + lr;
        unsigned long long pk =
            ((unsigned long long)xform(best) << 32) | (unsigned)(0xFFFFFFFFu - (unsigned)col);
        #pragma unroll
        for (int msk = 1; msk < 16; msk <<= 1) {
          unsigned long long o = __shfl_xor(pk, msk);
          if (o > pk) pk = o;
        }
        if (lr == 0) atomicMax(&rowPack[n0 + wr * 64 + fi * 16 + lg * 4 + r], pk);
      }
    }
    #pragma unroll
    for (int fj = 0; fj < 4; ++fj) {
      float cm = acc[0][fj][0];
      #pragma unroll
      for (int fi = 0; fi < 4; ++fi)
        #pragma unroll
        for (int r = 0; r < 4; ++r) cm = fmaxf(cm, acc[fi][fj][r]);
      cm = fmaxf(cm, __shfl_xor(cm, 16));
      cm = fmaxf(cm, __shfl_xor(cm, 32));
      if (lg == 0) atomicMax(&colMax[m0 + wc * 64 + fj * 16 + lr], xform(cm));
    }
  }

  if constexpr (MODE == 1) {
    __syncthreads();
    unsigned short(*bt)[130] = (unsigned short(*)[130])smraw;
    #pragma unroll
    for (int fi = 0; fi < 4; ++fi) {
      #pragma unroll
      for (int r = 0; r < 4; ++r) {
        int rowl = wr * 64 + fi * 16 + lg * 4 + r;
        float p = 0.f;
        #pragma unroll
        for (int fj = 0; fj < 4; ++fj) {
          float e = __expf(acc[fi][fj][r]);
          p += e;
          bt[rowl][wc * 64 + fj * 16 + lr] = f2bf(e);
        }
        #pragma unroll
        for (int msk = 1; msk < 16; msk <<= 1) p += __shfl_xor(p, msk);
        if (lr == 0) atomicAdd(&rowsum[n0 + rowl], p);
      }
    }
    __syncthreads();
    int row = tid >> 1, half = tid & 1;
    unsigned short* dst = Eout + (size_t)(n0 + row) * ldE + m0 + half * 64;
    const unsigned* su = (const unsigned*)(bt[row] + half * 64);
    #pragma unroll
    for (int i = 0; i < 8; ++i) {
      uint4 q4 = make_uint4(su[i * 4 + 0], su[i * 4 + 1], su[i * 4 + 2], su[i * 4 + 3]);
      *(uint4*)(dst + i * 8) = q4;
    }
  }

  if constexpr (MODE == 2) {
    float(*bt32)[132] = (float(*)[132])smraw;
    const int b = n0 >> 12, hw0 = n0 & 4095;
    #pragma unroll
    for (int h = 0; h < 2; ++h) {
      __syncthreads();
      if (wc == h) {
        #pragma unroll
        for (int fi = 0; fi < 4; ++fi) {
          #pragma unroll
          for (int r = 0; r < 4; ++r) {
            int rowl = wr * 64 + fi * 16 + lg * 4 + r;
            float inv = 1.0f / rsin[n0 + rowl];
            #pragma unroll
            for (int fj = 0; fj < 4; ++fj)
              bt32[fj * 16 + lr][rowl] = acc[fi][fj][r] * inv;
          }
        }
      }
      __syncthreads();
      float* ob = out + ((size_t)b * 2048 + chBase + m0 + h * 64) * 4096 + hw0;
      #pragma unroll
      for (int t = 0; t < 8; ++t) {
        int idx = t * 256 + tid;
        int row = idx >> 5;        // channel within this 64-half
        int off = (idx & 31) * 4;  // pixel offset, float4
        *(float4*)&ob[(size_t)row * 4096 + off] = *(const float4*)&bt32[row][off];
      }
    }
  }
}

// ---------------- w/col unpack + slot histogram ----------------
__global__ void kwcol(const unsigned long long* __restrict__ rowPack,
                      const unsigned* __restrict__ colMax,
                      float* __restrict__ w, int* __restrict__ col,
                      int* __restrict__ count) {
  int n = blockIdx.x * 256 + threadIdx.x;
  unsigned long long pk = rowPack[n];
  float smax = inv_xform((unsigned)(pk >> 32));
  int c = (int)(0xFFFFFFFFu - (unsigned)(pk & 0xFFFFFFFFu));
  w[n] = __expf(smax - inv_xform(colMax[c]));
  col[n] = c;
  atomicAdd(&count[c], 1);
}

// ---------------- exclusive prefix over 1024 counts ----------------
__global__ void kprefix(const int* __restrict__ count, int* __restrict__ start,
                        int* __restrict__ cursor) {
  __shared__ int sm[1024];
  int t = threadIdx.x;
  int v = count[t];
  sm[t] = v;
  __syncthreads();
  int acc = v;
  #pragma unroll
  for (int off = 1; off < 1024; off <<= 1) {
    int o = (t >= off) ? sm[t - off] : 0;
    __syncthreads();
    acc += o;
    sm[t] = acc;
    __syncthreads();
  }
  int ex = acc - v;  // exclusive prefix
  start[t] = ex;
  cursor[t] = ex;
}

// ---------------- bucket query indices by slot ----------------
__global__ void kfill(const int* __restrict__ col, int* __restrict__ cursor,
                      int* __restrict__ idx) {
  int n = blockIdx.x * 256 + threadIdx.x;
  int pos = atomicAdd(&cursor[col[n]], 1);
  idx[pos] = n;
}

// ---------------- gather segment-sum + mem add + l2norm (fused kmemupd) ----
__global__ __launch_bounds__(256) void kgathermem(
    const unsigned short* __restrict__ qf, const float* __restrict__ w,
    const int* __restrict__ idx, const int* __restrict__ start,
    const int* __restrict__ count, const float* __restrict__ mem,
    unsigned short* __restrict__ mu, unsigned short* __restrict__ muT) {
  __shared__ int sidx[1024];
  __shared__ float sw[1024];
  __shared__ float red[4];
  int m = blockIdx.x, t = threadIdx.x;
  int s = start[m], cnt = count[m];
  float a0 = 0.f, a1 = 0.f;
  for (int base = 0; base < cnt; base += 1024) {
    int lim = min(cnt - base, 1024);
    __syncthreads();
    for (int e = t; e < lim; e += 256) {
      int n = idx[s + base + e];
      sidx[e] = n;
      sw[e] = w[n];
    }
    __syncthreads();
    for (int e = 0; e < lim; ++e) {
      int n = sidx[e];
      float wn = sw[e];
      unsigned pv = *(const unsigned*)(qf + (size_t)n * 512 + 2 * t);
      a0 += wn * bf2f((unsigned short)(pv & 0xFFFFu));
      a1 += wn * bf2f((unsigned short)(pv >> 16));
    }
  }
  float2 mv = *(const float2*)(mem + (size_t)m * 512 + 2 * t);
  a0 += mv.x;
  a1 += mv.y;
  float ss = a0 * a0 + a1 * a1;
  #pragma unroll
  for (int k = 1; k < 64; k <<= 1) ss += __shfl_xor(ss, k);
  __syncthreads();
  if ((t & 63) == 0) red[t >> 6] = ss;
  __syncthreads();
  float tot = red[0] + red[1] + red[2] + red[3];
  float rn = 1.0f / fmaxf(sqrtf(tot), 1e-12f);
  unsigned short b0 = f2bf(a0 * rn), b1 = f2bf(a1 * rn);
  *(unsigned*)(mu + (size_t)m * 512 + 2 * t) = (unsigned)b0 | ((unsigned)b1 << 16);
  muT[(size_t)(2 * t) * 1024 + m] = b0;
  muT[(size_t)(2 * t + 1) * 1024 + m] = b1;
}

extern "C" void kernel_launch(void* const* d_in, const int* in_sizes, int n_in,
                              void* d_out, int out_size, void* d_ws, size_t ws_size,
                              hipStream_t stream) {
  const float* feat = (const float*)d_in[0];
  const float* memR = (const float*)d_in[2];
  const float* memF = (const float*)d_in[3];
  float* out = (float*)d_out;
  char* ws = (char*)d_ws;

  size_t off = 0;
  auto alloc = [&](size_t bytes) {
    void* p = ws + off;
    off += (bytes + 255) & ~(size_t)255;
    return p;
  };
  unsigned short* qf = (unsigned short*)alloc(33554432);   // [32768,512] bf16
  unsigned short* E = (unsigned short*)alloc(67108864);    // [32768,1024] bf16
  unsigned long long* rowPack = (unsigned long long*)alloc(262144);  // zero start
  unsigned* colMax = (unsigned*)alloc(4096);
  float* rowsum = (float*)alloc(131072);
  int* count = (int*)alloc(4096);
  int* cursor = (int*)alloc(4096);                         // zero end
  size_t zero_bytes = ((char*)cursor + 4096) - (char*)rowPack;
  int* start = (int*)alloc(4096);
  float* w = (float*)alloc(131072);
  int* col = (int*)alloc(131072);
  int* idx = (int*)alloc(131072);
  unsigned short* mu = (unsigned short*)alloc(1048576);    // [1024,512] bf16
  unsigned short* muT = (unsigned short*)alloc(1048576);   // [512,1024] bf16
  unsigned short* memRb = (unsigned short*)alloc(1048576);
  unsigned short* memFb = (unsigned short*)alloc(1048576);
  float* rnorm = (float*)alloc(131072);
  if (off > ws_size) return;  // workspace too small: fail validation cleanly

  kcvt<<<2048, 256, 0, stream>>>(memR, memRb, 524288);
  kcvt<<<2048, 256, 0, stream>>>(memF, memFb, 524288);
  knorm<<<512, 256, 0, stream>>>(feat, rnorm);
  kqf<<<dim3(8, 512), 256, 0, stream>>>(feat, rnorm, qf, out);

  for (int br = 0; br < 2; ++br) {
    const unsigned short* mb = br ? memFb : memRb;
    const float* mf = br ? memF : memR;
    int chBase = 512 + br * 1024;
    hipMemsetAsync(rowPack, 0, zero_bytes, stream);
    gemm128<0><<<dim3(8, 256), 256, 0, stream>>>(qf, mb, 512, 0, rowPack, colMax,
                                                 nullptr, nullptr, nullptr, nullptr, 0);
    kwcol<<<128, 256, 0, stream>>>(rowPack, colMax, w, col, count);
    kprefix<<<1, 1024, 0, stream>>>(count, start, cursor);
    kfill<<<128, 256, 0, stream>>>(col, cursor, idx);
    kgathermem<<<1024, 256, 0, stream>>>(qf, w, idx, start, count, mf, mu, muT);
    gemm128<1><<<dim3(8, 256), 256, 0, stream>>>(qf, mu, 512, 1024, nullptr, nullptr,
                                                 E, rowsum, nullptr, nullptr, 0);
    gemm128<2><<<dim3(4, 256), 256, 0, stream>>>(E, muT, 1024, 0, nullptr, nullptr,
                                                 nullptr, nullptr, out, rowsum, chBase);
  }
}

// Round 4
// 567.621 us; speedup vs baseline: 2.5409x; 1.0139x over previous
//
#include <hip/hip_runtime.h>
#include <stdint.h>

typedef __attribute__((ext_vector_type(8))) short bf16x8;
typedef __attribute__((ext_vector_type(4))) float f32x4;

__device__ __forceinline__ unsigned short f2bf(float f) {
  unsigned u = __float_as_uint(f);
  u += 0x7FFFu + ((u >> 16) & 1u);
  return (unsigned short)(u >> 16);
}
__device__ __forceinline__ float bf2f(unsigned short b) {
  return __uint_as_float(((unsigned)b) << 16);
}
// monotone float->u32 transform (order-preserving), and inverse
__device__ __forceinline__ unsigned xform(float s) {
  unsigned u = __float_as_uint(s);
  return (u & 0x80000000u) ? ~u : (u | 0x80000000u);
}
__device__ __forceinline__ float inv_xform(unsigned t) {
  unsigned u = (t & 0x80000000u) ? (t & 0x7FFFFFFFu) : ~t;
  return __uint_as_float(u);
}

__device__ __forceinline__ void gl_lds16(const void* g, void* l) {
  __builtin_amdgcn_global_load_lds(
      (const __attribute__((address_space(1))) unsigned*)g,
      (__attribute__((address_space(3))) unsigned*)l, 16, 0, 0);
}

// ---------------- mem fp32 -> bf16 ----------------
__global__ void kcvt(const float* __restrict__ a, unsigned short* __restrict__ o, int n) {
  int i = blockIdx.x * 256 + threadIdx.x;
  if (i < n) o[i] = f2bf(a[i]);
}

// ------- fused: per-pixel l2norm + q fp32 out (both regions) + qf bf16 -------
// q = feat/||feat|| (mask scaling is uniform over channels, cancels in l2norm)
// Each block: 64 pixels; wave wv owns channels [wv*128, wv*128+128).
__global__ __launch_bounds__(256) void kqf2(const float* __restrict__ feat,
                                            unsigned short* __restrict__ qf,
                                            float* __restrict__ out) {
  int n0 = blockIdx.x * 64;
  int lane = threadIdx.x & 63, wv = threadIdx.x >> 6;
  int b = n0 >> 12, hw0 = n0 & 4095;
  const float* fp = feat + (size_t)b * (512 * 4096) + (size_t)(wv * 128) * 4096 + hw0 + lane;
  unsigned pk[64];
  float ss = 0.f;
  #pragma unroll
  for (int i = 0; i < 64; ++i) {
    float v0 = fp[(size_t)(2 * i) * 4096];
    float v1 = fp[(size_t)(2 * i + 1) * 4096];
    ss += v0 * v0 + v1 * v1;
    pk[i] = (unsigned)f2bf(v0) | ((unsigned)f2bf(v1) << 16);
  }
  __shared__ float red[4][64];
  red[wv][lane] = ss;
  __syncthreads();
  float tot = red[0][lane] + red[1][lane] + red[2][lane] + red[3][lane];
  float rn = 1.0f / fmaxf(sqrtf(tot), 1e-12f);
  float* ob = out + ((size_t)b * 2048 + wv * 128) * 4096 + hw0 + lane;
  unsigned short* qp = qf + (size_t)(n0 + lane) * 512 + wv * 128;
  #pragma unroll
  for (int i = 0; i < 64; ++i) {
    unsigned short h0 = (unsigned short)(pk[i] & 0xFFFFu);
    unsigned short h1 = (unsigned short)(pk[i] >> 16);
    float q0 = bf2f(h0) * rn;
    float q1 = bf2f(h1) * rn;
    ob[(size_t)(2 * i) * 4096] = q0;
    ob[(size_t)(2 * i) * 4096 + (size_t)1024 * 4096] = q0;
    ob[(size_t)(2 * i + 1) * 4096] = q1;
    ob[(size_t)(2 * i + 1) * 4096 + (size_t)1024 * 4096] = q1;
    *(unsigned*)(qp + 2 * i) = (unsigned)f2bf(q0) | ((unsigned)f2bf(q1) << 16);
  }
}

// ---------------- GEMM (A[*,K] x B[*,K]^T), 128x128 tile, fused epilogues ----
// 1D grid with bijective XCD swizzle: blocks sharing an A-panel (same n0,
// all GX m0-values) land consecutively on ONE XCD -> A fetched once per XCD.
// MODE 0: score pass  -> rowPack (u64 max: score|col) + colMax (u32 max)
// MODE 1: read pass   -> E = exp(score2) bf16 + rowsum atomics
// MODE 2: PV pass     -> out = (E @ muT)/rowsum, fp32 transposed store to d_out
template <int MODE, int GX>
__global__ __launch_bounds__(256) void gemm128(
    const unsigned short* __restrict__ A, const unsigned short* __restrict__ B,
    int K, int ldE,
    unsigned long long* __restrict__ rowPack, unsigned* __restrict__ colMax,
    unsigned short* __restrict__ Eout, float* __restrict__ rowsum,
    float* __restrict__ out, const float* __restrict__ rsin, int chBase) {
  __shared__ __align__(16) unsigned char smraw[33792];
  unsigned short* As = (unsigned short*)smraw;
  unsigned short* Bs = As + 8192;
  const int bid = blockIdx.x;
  const int xcd = bid & 7;
  const int t = bid >> 3;
  const int m0 = (t % GX) * 128;
  const int n0 = (xcd + (t / GX) * 8) * 128;
  const int tid = threadIdx.x;
  const int wid = tid >> 6, lane = tid & 63;
  const int wr = wid >> 1, wc = wid & 1;
  const int lr = lane & 15, lg = lane >> 4;
  const int srow = lane >> 3, scol = (lane & 7) * 8;

  f32x4 acc[4][4];
  #pragma unroll
  for (int i = 0; i < 4; ++i)
    #pragma unroll
    for (int j = 0; j < 4; ++j) acc[i][j] = (f32x4){0.f, 0.f, 0.f, 0.f};

  for (int k0 = 0; k0 < K; k0 += 64) {
    __syncthreads();
    #pragma unroll
    for (int i = 0; i < 4; ++i) {
      int ci = wid * 4 + i;
      int row = ci * 8 + srow;
      gl_lds16(A + (size_t)(n0 + row) * K + k0 + scol, As + ci * 512);
      gl_lds16(B + (size_t)(m0 + row) * K + k0 + scol, Bs + ci * 512);
    }
    __syncthreads();
    #pragma unroll
    for (int kk = 0; kk < 64; kk += 32) {
      bf16x8 af[4], bfr[4];
      #pragma unroll
      for (int f = 0; f < 4; ++f)
        af[f] = *(const bf16x8*)&As[(wr * 64 + f * 16 + lr) * 64 + kk + lg * 8];
      #pragma unroll
      for (int f = 0; f < 4; ++f)
        bfr[f] = *(const bf16x8*)&Bs[(wc * 64 + f * 16 + lr) * 64 + kk + lg * 8];
      #pragma unroll
      for (int fi = 0; fi < 4; ++fi)
        #pragma unroll
        for (int fj = 0; fj < 4; ++fj)
          acc[fi][fj] = __builtin_amdgcn_mfma_f32_16x16x32_bf16(af[fi], bfr[fj], acc[fi][fj], 0, 0, 0);
    }
  }
  // D frag mapping (verified m89): col = lr (+fj*16), row = lg*4+r (+fi*16)

  if constexpr (MODE == 0) {
    #pragma unroll
    for (int fi = 0; fi < 4; ++fi) {
      #pragma unroll
      for (int r = 0; r < 4; ++r) {
        float best = acc[fi][0][r];
        int bj = 0;
        #pragma unroll
        for (int fj = 1; fj < 4; ++fj) {
          float v = acc[fi][fj][r];
          if (v > best) { best = v; bj = fj; }
        }
        int col = m0 + wc * 64 + bj * 16 + lr;
        unsigned long long pk =
            ((unsigned long long)xform(best) << 32) | (unsigned)(0xFFFFFFFFu - (unsigned)col);
        #pragma unroll
        for (int msk = 1; msk < 16; msk <<= 1) {
          unsigned long long o = __shfl_xor(pk, msk);
          if (o > pk) pk = o;
        }
        if (lr == 0) atomicMax(&rowPack[n0 + wr * 64 + fi * 16 + lg * 4 + r], pk);
      }
    }
    #pragma unroll
    for (int fj = 0; fj < 4; ++fj) {
      float cm = acc[0][fj][0];
      #pragma unroll
      for (int fi = 0; fi < 4; ++fi)
        #pragma unroll
        for (int r = 0; r < 4; ++r) cm = fmaxf(cm, acc[fi][fj][r]);
      cm = fmaxf(cm, __shfl_xor(cm, 16));
      cm = fmaxf(cm, __shfl_xor(cm, 32));
      if (lg == 0) atomicMax(&colMax[m0 + wc * 64 + fj * 16 + lr], xform(cm));
    }
  }

  if constexpr (MODE == 1) {
    __syncthreads();
    unsigned short(*bt)[130] = (unsigned short(*)[130])smraw;
    #pragma unroll
    for (int fi = 0; fi < 4; ++fi) {
      #pragma unroll
      for (int r = 0; r < 4; ++r) {
        int rowl = wr * 64 + fi * 16 + lg * 4 + r;
        float p = 0.f;
        #pragma unroll
        for (int fj = 0; fj < 4; ++fj) {
          float e = __expf(acc[fi][fj][r]);
          p += e;
          bt[rowl][wc * 64 + fj * 16 + lr] = f2bf(e);
        }
        #pragma unroll
        for (int msk = 1; msk < 16; msk <<= 1) p += __shfl_xor(p, msk);
        if (lr == 0) atomicAdd(&rowsum[n0 + rowl], p);
      }
    }
    __syncthreads();
    int row = tid >> 1, half = tid & 1;
    unsigned short* dst = Eout + (size_t)(n0 + row) * ldE + m0 + half * 64;
    const unsigned* su = (const unsigned*)(bt[row] + half * 64);
    #pragma unroll
    for (int i = 0; i < 8; ++i) {
      uint4 q4 = make_uint4(su[i * 4 + 0], su[i * 4 + 1], su[i * 4 + 2], su[i * 4 + 3]);
      *(uint4*)(dst + i * 8) = q4;
    }
  }

  if constexpr (MODE == 2) {
    float(*bt32)[132] = (float(*)[132])smraw;
    const int b = n0 >> 12, hw0 = n0 & 4095;
    #pragma unroll
    for (int h = 0; h < 2; ++h) {
      __syncthreads();
      if (wc == h) {
        #pragma unroll
        for (int fi = 0; fi < 4; ++fi) {
          #pragma unroll
          for (int r = 0; r < 4; ++r) {
            int rowl = wr * 64 + fi * 16 + lg * 4 + r;
            float inv = 1.0f / rsin[n0 + rowl];
            #pragma unroll
            for (int fj = 0; fj < 4; ++fj)
              bt32[fj * 16 + lr][rowl] = acc[fi][fj][r] * inv;
          }
        }
      }
      __syncthreads();
      float* ob = out + ((size_t)b * 2048 + chBase + m0 + h * 64) * 4096 + hw0;
      #pragma unroll
      for (int tt = 0; tt < 8; ++tt) {
        int idx = tt * 256 + tid;
        int row = idx >> 5;        // channel within this 64-half
        int off = (idx & 31) * 4;  // pixel offset, float4
        *(float4*)&ob[(size_t)row * 4096 + off] = *(const float4*)&bt32[row][off];
      }
    }
  }
}

// ---------------- w/col unpack + slot histogram ----------------
__global__ void kwcol(const unsigned long long* __restrict__ rowPack,
                      const unsigned* __restrict__ colMax,
                      float* __restrict__ w, int* __restrict__ col,
                      int* __restrict__ count) {
  int n = blockIdx.x * 256 + threadIdx.x;
  unsigned long long pk = rowPack[n];
  float smax = inv_xform((unsigned)(pk >> 32));
  int c = (int)(0xFFFFFFFFu - (unsigned)(pk & 0xFFFFFFFFu));
  w[n] = __expf(smax - inv_xform(colMax[c]));
  col[n] = c;
  atomicAdd(&count[c], 1);
}

// ---------------- exclusive prefix over 1024 counts ----------------
__global__ void kprefix(const int* __restrict__ count, int* __restrict__ start,
                        int* __restrict__ cursor) {
  __shared__ int sm[1024];
  int t = threadIdx.x;
  int v = count[t];
  sm[t] = v;
  __syncthreads();
  int acc = v;
  #pragma unroll
  for (int off = 1; off < 1024; off <<= 1) {
    int o = (t >= off) ? sm[t - off] : 0;
    __syncthreads();
    acc += o;
    sm[t] = acc;
    __syncthreads();
  }
  int ex = acc - v;  // exclusive prefix
  start[t] = ex;
  cursor[t] = ex;
}

// ---------------- bucket query indices by slot ----------------
__global__ void kfill(const int* __restrict__ col, int* __restrict__ cursor,
                      int* __restrict__ idx) {
  int n = blockIdx.x * 256 + threadIdx.x;
  int pos = atomicAdd(&cursor[col[n]], 1);
  idx[pos] = n;
}

// ---------------- gather segment-sum + mem add + l2norm (fused) ----
__global__ __launch_bounds__(256) void kgathermem(
    const unsigned short* __restrict__ qf, const float* __restrict__ w,
    const int* __restrict__ idx, const int* __restrict__ start,
    const int* __restrict__ count, const float* __restrict__ mem,
    unsigned short* __restrict__ mu, unsigned short* __restrict__ muT) {
  __shared__ int sidx[1024];
  __shared__ float sw[1024];
  __shared__ float red[4];
  int m = blockIdx.x, t = threadIdx.x;
  int s = start[m], cnt = count[m];
  float a0 = 0.f, a1 = 0.f;
  for (int base = 0; base < cnt; base += 1024) {
    int lim = min(cnt - base, 1024);
    __syncthreads();
    for (int e = t; e < lim; e += 256) {
      int n = idx[s + base + e];
      sidx[e] = n;
      sw[e] = w[n];
    }
    __syncthreads();
    for (int e = 0; e < lim; ++e) {
      int n = sidx[e];
      float wn = sw[e];
      unsigned pv = *(const unsigned*)(qf + (size_t)n * 512 + 2 * t);
      a0 += wn * bf2f((unsigned short)(pv & 0xFFFFu));
      a1 += wn * bf2f((unsigned short)(pv >> 16));
    }
  }
  float2 mv = *(const float2*)(mem + (size_t)m * 512 + 2 * t);
  a0 += mv.x;
  a1 += mv.y;
  float ss = a0 * a0 + a1 * a1;
  #pragma unroll
  for (int k = 1; k < 64; k <<= 1) ss += __shfl_xor(ss, k);
  __syncthreads();
  if ((t & 63) == 0) red[t >> 6] = ss;
  __syncthreads();
  float tot = red[0] + red[1] + red[2] + red[3];
  float rn = 1.0f / fmaxf(sqrtf(tot), 1e-12f);
  unsigned short b0 = f2bf(a0 * rn), b1 = f2bf(a1 * rn);
  *(unsigned*)(mu + (size_t)m * 512 + 2 * t) = (unsigned)b0 | ((unsigned)b1 << 16);
  muT[(size_t)(2 * t) * 1024 + m] = b0;
  muT[(size_t)(2 * t + 1) * 1024 + m] = b1;
}

extern "C" void kernel_launch(void* const* d_in, const int* in_sizes, int n_in,
                              void* d_out, int out_size, void* d_ws, size_t ws_size,
                              hipStream_t stream) {
  const float* feat = (const float*)d_in[0];
  const float* memR = (const float*)d_in[2];
  const float* memF = (const float*)d_in[3];
  float* out = (float*)d_out;
  char* ws = (char*)d_ws;

  size_t off = 0;
  auto alloc = [&](size_t bytes) {
    void* p = ws + off;
    off += (bytes + 255) & ~(size_t)255;
    return p;
  };
  unsigned short* qf = (unsigned short*)alloc(33554432);   // [32768,512] bf16
  unsigned short* E = (unsigned short*)alloc(67108864);    // [32768,1024] bf16
  unsigned long long* rowPack = (unsigned long long*)alloc(262144);  // zero start
  unsigned* colMax = (unsigned*)alloc(4096);
  float* rowsum = (float*)alloc(131072);
  int* count = (int*)alloc(4096);
  int* cursor = (int*)alloc(4096);                         // zero end
  size_t zero_bytes = ((char*)cursor + 4096) - (char*)rowPack;
  int* start = (int*)alloc(4096);
  float* w = (float*)alloc(131072);
  int* col = (int*)alloc(131072);
  int* idx = (int*)alloc(131072);
  unsigned short* mu = (unsigned short*)alloc(1048576);    // [1024,512] bf16
  unsigned short* muT = (unsigned short*)alloc(1048576);   // [512,1024] bf16
  unsigned short* memRb = (unsigned short*)alloc(1048576);
  unsigned short* memFb = (unsigned short*)alloc(1048576);
  if (off > ws_size) return;  // workspace too small: fail validation cleanly

  kcvt<<<2048, 256, 0, stream>>>(memR, memRb, 524288);
  kcvt<<<2048, 256, 0, stream>>>(memF, memFb, 524288);
  kqf2<<<512, 256, 0, stream>>>(feat, qf, out);

  for (int br = 0; br < 2; ++br) {
    const unsigned short* mb = br ? memFb : memRb;
    const float* mf = br ? memF : memR;
    int chBase = 512 + br * 1024;
    hipMemsetAsync(rowPack, 0, zero_bytes, stream);
    gemm128<0, 8><<<2048, 256, 0, stream>>>(qf, mb, 512, 0, rowPack, colMax,
                                            nullptr, nullptr, nullptr, nullptr, 0);
    kwcol<<<128, 256, 0, stream>>>(rowPack, colMax, w, col, count);
    kprefix<<<1, 1024, 0, stream>>>(count, start, cursor);
    kfill<<<128, 256, 0, stream>>>(col, cursor, idx);
    kgathermem<<<1024, 256, 0, stream>>>(qf, w, idx, start, count, mf, mu, muT);
    gemm128<1, 8><<<2048, 256, 0, stream>>>(qf, mu, 512, 1024, nullptr, nullptr,
                                            E, rowsum, nullptr, nullptr, 0);
    gemm128<2, 4><<<1024, 256, 0, stream>>>(E, muT, 1024, 0, nullptr, nullptr,
                                            nullptr, nullptr, out, rowsum, chBase);
  }
}

// Round 5
// 527.636 us; speedup vs baseline: 2.7334x; 1.0758x over previous
//
#include <hip/hip_runtime.h>
#include <stdint.h>

typedef __attribute__((ext_vector_type(8))) short bf16x8;
typedef __attribute__((ext_vector_type(4))) float f32x4;

__device__ __forceinline__ unsigned short f2bf(float f) {
  unsigned u = __float_as_uint(f);
  u += 0x7FFFu + ((u >> 16) & 1u);
  return (unsigned short)(u >> 16);
}
__device__ __forceinline__ float bf2f(unsigned short b) {
  return __uint_as_float(((unsigned)b) << 16);
}
// monotone float->u32 transform (order-preserving), and inverse
__device__ __forceinline__ unsigned xform(float s) {
  unsigned u = __float_as_uint(s);
  return (u & 0x80000000u) ? ~u : (u | 0x80000000u);
}
__device__ __forceinline__ float inv_xform(unsigned t) {
  unsigned u = (t & 0x80000000u) ? (t & 0x7FFFFFFFu) : ~t;
  return __uint_as_float(u);
}

__device__ __forceinline__ void gl_lds16(const void* g, void* l) {
  __builtin_amdgcn_global_load_lds(
      (const __attribute__((address_space(1))) unsigned*)g,
      (__attribute__((address_space(3))) unsigned*)l, 16, 0, 0);
}

// ---------------- both mems fp32 -> bf16 into concat buffer [2048,512] -------
__global__ void kcvt2(const float* __restrict__ memR, const float* __restrict__ memF,
                      unsigned short* __restrict__ memB) {
  int i = blockIdx.x * 256 + threadIdx.x;  // 0..1048575
  const float* src = (i < 524288) ? memR : memF;
  memB[i] = f2bf(src[i & 524287]);
}

// ------- fused: per-pixel l2norm + q fp32 out (both regions) + qf bf16 -------
// q = feat/||feat|| (mask scaling is uniform over channels, cancels in l2norm)
// qf written via XOR-swizzled LDS transpose -> fully coalesced global stores.
__global__ __launch_bounds__(256) void kqf2(const float* __restrict__ feat,
                                            unsigned* __restrict__ qf32,
                                            float* __restrict__ out) {
  __shared__ unsigned buf[32 * 256];  // 32 KiB
  __shared__ float red[4][64];
  int n0 = blockIdx.x * 64;
  int lane = threadIdx.x & 63, wv = threadIdx.x >> 6;
  int b = n0 >> 12, hw0 = n0 & 4095;
  const float* fp = feat + (size_t)b * (512 * 4096) + (size_t)(wv * 128) * 4096 + hw0 + lane;
  unsigned pk[64];
  float ss = 0.f;
  #pragma unroll
  for (int i = 0; i < 64; ++i) {
    float v0 = fp[(size_t)(2 * i) * 4096];
    float v1 = fp[(size_t)(2 * i + 1) * 4096];
    ss += v0 * v0 + v1 * v1;
    pk[i] = (unsigned)f2bf(v0) | ((unsigned)f2bf(v1) << 16);
  }
  red[wv][lane] = ss;
  __syncthreads();
  float tot = red[0][lane] + red[1][lane] + red[2][lane] + red[3][lane];
  float rn = 1.0f / fmaxf(sqrtf(tot), 1e-12f);
  float* ob = out + ((size_t)b * 2048 + wv * 128) * 4096 + hw0 + lane;
  #pragma unroll
  for (int i = 0; i < 64; ++i) {
    float q0 = bf2f((unsigned short)(pk[i] & 0xFFFFu)) * rn;
    float q1 = bf2f((unsigned short)(pk[i] >> 16)) * rn;
    ob[(size_t)(2 * i) * 4096] = q0;
    ob[(size_t)(2 * i) * 4096 + (size_t)1024 * 4096] = q0;
    ob[(size_t)(2 * i + 1) * 4096] = q1;
    ob[(size_t)(2 * i + 1) * 4096 + (size_t)1024 * 4096] = q1;
    pk[i] = (unsigned)f2bf(q0) | ((unsigned)f2bf(q1) << 16);
  }
  // two transpose passes (32 pixel-rows each) through XOR-swizzled LDS
  #pragma unroll
  for (int p = 0; p < 2; ++p) {
    __syncthreads();
    if ((lane >> 5) == p) {
      int px = lane & 31;
      #pragma unroll
      for (int i = 0; i < 64; ++i) buf[px * 256 + ((wv * 64 + i) ^ px)] = pk[i];
    }
    __syncthreads();
    #pragma unroll
    for (int r = 0; r < 32; ++r) {
      int row = p * 32 + r;
      qf32[(size_t)(n0 + row) * 256 + threadIdx.x] = buf[r * 256 + (threadIdx.x ^ r)];
    }
  }
}

// -------- merged GEMM (A[*,K] x B[*,K]^T), 128x128 tile, fused epilogues ----
// Both branches in one dispatch (B is branch-concat along rows / M dim).
// 1D grid with bijective XCD swizzle (blocks sharing an A-panel stay on one XCD).
// MODE 0: score pass  -> rowPackAll (u64 max) + colMaxAll (u32 max); br = m0>>10
// MODE 1: read pass   -> E[n, 2048] = exp(score2) bf16 + rowsumAll atomics
// MODE 2: PV pass     -> out = (E_br @ muT)/rowsum, fp32 transposed store; br = m0>>9
template <int MODE, int LGX>
__global__ __launch_bounds__(256) void gemmM(
    const unsigned short* __restrict__ A, const unsigned short* __restrict__ B,
    int K, int lda, int ldb,
    unsigned long long* __restrict__ rowPackAll, unsigned* __restrict__ colMaxAll,
    unsigned short* __restrict__ Eout, float* __restrict__ rowsumAll,
    float* __restrict__ out) {
  __shared__ __align__(16) unsigned char smraw[33792];
  unsigned short* As = (unsigned short*)smraw;
  unsigned short* Bs = As + 8192;
  const int bid = blockIdx.x;
  const int xcd = bid & 7;
  const int tt0 = bid >> 3;
  const int m0 = (tt0 & ((1 << LGX) - 1)) * 128;
  const int n0 = (xcd + (tt0 >> LGX) * 8) * 128;
  const int tid = threadIdx.x;
  const int wid = tid >> 6, lane = tid & 63;
  const int wr = wid >> 1, wc = wid & 1;
  const int lr = lane & 15, lg = lane >> 4;
  const int srow = lane >> 3, scol = (lane & 7) * 8;
  const size_t brOffA = (MODE == 2) ? (size_t)((m0 >> 9) * 1024) : 0;

  f32x4 acc[4][4];
  #pragma unroll
  for (int i = 0; i < 4; ++i)
    #pragma unroll
    for (int j = 0; j < 4; ++j) acc[i][j] = (f32x4){0.f, 0.f, 0.f, 0.f};

  for (int k0 = 0; k0 < K; k0 += 64) {
    __syncthreads();
    #pragma unroll
    for (int i = 0; i < 4; ++i) {
      int ci = wid * 4 + i;
      int row = ci * 8 + srow;
      gl_lds16(A + brOffA + (size_t)(n0 + row) * lda + k0 + scol, As + ci * 512);
      gl_lds16(B + (size_t)(m0 + row) * ldb + k0 + scol, Bs + ci * 512);
    }
    __syncthreads();
    #pragma unroll
    for (int kk = 0; kk < 64; kk += 32) {
      bf16x8 af[4], bfr[4];
      #pragma unroll
      for (int f = 0; f < 4; ++f)
        af[f] = *(const bf16x8*)&As[(wr * 64 + f * 16 + lr) * 64 + kk + lg * 8];
      #pragma unroll
      for (int f = 0; f < 4; ++f)
        bfr[f] = *(const bf16x8*)&Bs[(wc * 64 + f * 16 + lr) * 64 + kk + lg * 8];
      #pragma unroll
      for (int fi = 0; fi < 4; ++fi)
        #pragma unroll
        for (int fj = 0; fj < 4; ++fj)
          acc[fi][fj] = __builtin_amdgcn_mfma_f32_16x16x32_bf16(af[fi], bfr[fj], acc[fi][fj], 0, 0, 0);
    }
  }
  // D frag mapping (verified m89): col = lr (+fj*16), row = lg*4+r (+fi*16)

  if constexpr (MODE == 0) {
    const int br = m0 >> 10;
    #pragma unroll
    for (int fi = 0; fi < 4; ++fi) {
      #pragma unroll
      for (int r = 0; r < 4; ++r) {
        float best = acc[fi][0][r];
        int bj = 0;
        #pragma unroll
        for (int fj = 1; fj < 4; ++fj) {
          float v = acc[fi][fj][r];
          if (v > best) { best = v; bj = fj; }
        }
        int slot = (m0 + wc * 64 + bj * 16 + lr) & 1023;
        unsigned long long pk =
            ((unsigned long long)xform(best) << 32) | (unsigned)(0xFFFFFFFFu - (unsigned)slot);
        #pragma unroll
        for (int msk = 1; msk < 16; msk <<= 1) {
          unsigned long long o = __shfl_xor(pk, msk);
          if (o > pk) pk = o;
        }
        if (lr == 0)
          atomicMax(&rowPackAll[(size_t)br * 32768 + n0 + wr * 64 + fi * 16 + lg * 4 + r], pk);
      }
    }
    #pragma unroll
    for (int fj = 0; fj < 4; ++fj) {
      float cm = acc[0][fj][0];
      #pragma unroll
      for (int fi = 0; fi < 4; ++fi)
        #pragma unroll
        for (int r = 0; r < 4; ++r) cm = fmaxf(cm, acc[fi][fj][r]);
      cm = fmaxf(cm, __shfl_xor(cm, 16));
      cm = fmaxf(cm, __shfl_xor(cm, 32));
      if (lg == 0) atomicMax(&colMaxAll[m0 + wc * 64 + fj * 16 + lr], xform(cm));
    }
  }

  if constexpr (MODE == 1) {
    const int br = m0 >> 10;
    __syncthreads();
    unsigned short(*bt)[130] = (unsigned short(*)[130])smraw;
    #pragma unroll
    for (int fi = 0; fi < 4; ++fi) {
      #pragma unroll
      for (int r = 0; r < 4; ++r) {
        int rowl = wr * 64 + fi * 16 + lg * 4 + r;
        float p = 0.f;
        #pragma unroll
        for (int fj = 0; fj < 4; ++fj) {
          float e = __expf(acc[fi][fj][r]);
          p += e;
          bt[rowl][wc * 64 + fj * 16 + lr] = f2bf(e);
        }
        #pragma unroll
        for (int msk = 1; msk < 16; msk <<= 1) p += __shfl_xor(p, msk);
        if (lr == 0) atomicAdd(&rowsumAll[(size_t)br * 32768 + n0 + rowl], p);
      }
    }
    __syncthreads();
    int row = tid >> 1, half = tid & 1;
    unsigned short* dst = Eout + (size_t)(n0 + row) * 2048 + m0 + half * 64;
    const unsigned* su = (const unsigned*)(bt[row] + half * 64);
    #pragma unroll
    for (int i = 0; i < 8; ++i) {
      uint4 q4 = make_uint4(su[i * 4 + 0], su[i * 4 + 1], su[i * 4 + 2], su[i * 4 + 3]);
      *(uint4*)(dst + i * 8) = q4;
    }
  }

  if constexpr (MODE == 2) {
    const int br = m0 >> 9;
    const int m0l = m0 & 511;
    float(*bt32)[132] = (float(*)[132])smraw;
    const int b = n0 >> 12, hw0 = n0 & 4095;
    const float* rs = rowsumAll + (size_t)br * 32768;
    #pragma unroll
    for (int h = 0; h < 2; ++h) {
      __syncthreads();
      if (wc == h) {
        #pragma unroll
        for (int fi = 0; fi < 4; ++fi) {
          #pragma unroll
          for (int r = 0; r < 4; ++r) {
            int rowl = wr * 64 + fi * 16 + lg * 4 + r;
            float inv = 1.0f / rs[n0 + rowl];
            #pragma unroll
            for (int fj = 0; fj < 4; ++fj)
              bt32[fj * 16 + lr][rowl] = acc[fi][fj][r] * inv;
          }
        }
      }
      __syncthreads();
      float* ob = out + ((size_t)b * 2048 + 512 + br * 1024 + m0l + h * 64) * 4096 + hw0;
      #pragma unroll
      for (int t8 = 0; t8 < 8; ++t8) {
        int idx = t8 * 256 + tid;
        int row = idx >> 5;        // channel within this 64-half
        int off = (idx & 31) * 4;  // pixel offset, float4
        *(float4*)&ob[(size_t)row * 4096 + off] = *(const float4*)&bt32[row][off];
      }
    }
  }
}

// ---------------- w/col unpack + slot histogram (both branches) --------------
__global__ void kwcol(const unsigned long long* __restrict__ rowPackAll,
                      const unsigned* __restrict__ colMaxAll,
                      float* __restrict__ wArr, int* __restrict__ colArr,
                      int* __restrict__ count) {
  int br = blockIdx.y;
  int n = blockIdx.x * 256 + threadIdx.x;
  unsigned long long pk = rowPackAll[(size_t)br * 32768 + n];
  float smax = inv_xform((unsigned)(pk >> 32));
  int slot = (int)(0xFFFFFFFFu - (unsigned)(pk & 0xFFFFFFFFu));
  wArr[(size_t)br * 32768 + n] = __expf(smax - inv_xform(colMaxAll[br * 1024 + slot]));
  colArr[(size_t)br * 32768 + n] = slot;
  atomicAdd(&count[br * 1024 + slot], 1);
}

// ---------------- exclusive prefix over 1024 counts (per branch) -------------
__global__ void kprefix(const int* __restrict__ count, int* __restrict__ start,
                        int* __restrict__ cursor) {
  __shared__ int sm[1024];
  int br = blockIdx.x;
  int t = threadIdx.x;
  int v = count[br * 1024 + t];
  sm[t] = v;
  __syncthreads();
  int acc = v;
  #pragma unroll
  for (int off = 1; off < 1024; off <<= 1) {
    int o = (t >= off) ? sm[t - off] : 0;
    __syncthreads();
    acc += o;
    sm[t] = acc;
    __syncthreads();
  }
  int ex = acc - v;  // exclusive prefix (branch-local)
  start[br * 1024 + t] = ex;
  cursor[br * 1024 + t] = ex;
}

// ---------------- bucket query indices by slot (both branches) ---------------
__global__ void kfill(const int* __restrict__ colArr, int* __restrict__ cursor,
                      int* __restrict__ idxArr) {
  int br = blockIdx.y;
  int n = blockIdx.x * 256 + threadIdx.x;
  int pos = atomicAdd(&cursor[br * 1024 + colArr[(size_t)br * 32768 + n]], 1);
  idxArr[(size_t)br * 32768 + pos] = n;
}

// ------- gather segment-sum + mem add + l2norm -> mu (concat) + muT (concat) -
__global__ __launch_bounds__(256) void kgathermem(
    const unsigned short* __restrict__ qf, const float* __restrict__ wArr,
    const int* __restrict__ idxArr, const int* __restrict__ start,
    const int* __restrict__ count, const float* __restrict__ memR,
    const float* __restrict__ memF,
    unsigned short* __restrict__ mu, unsigned short* __restrict__ muT) {
  __shared__ int sidx[1024];
  __shared__ float sw[1024];
  __shared__ float red[4];
  int m = blockIdx.x, br = blockIdx.y, t = threadIdx.x;
  int s = start[br * 1024 + m], cnt = count[br * 1024 + m];
  const int* idx = idxArr + (size_t)br * 32768;
  const float* w = wArr + (size_t)br * 32768;
  const float* mem = br ? memF : memR;
  float a0 = 0.f, a1 = 0.f;
  for (int base = 0; base < cnt; base += 1024) {
    int lim = min(cnt - base, 1024);
    __syncthreads();
    for (int e = t; e < lim; e += 256) {
      int n = idx[s + base + e];
      sidx[e] = n;
      sw[e] = w[n];
    }
    __syncthreads();
    for (int e = 0; e < lim; ++e) {
      int n = sidx[e];
      float wn = sw[e];
      unsigned pv = *(const unsigned*)(qf + (size_t)n * 512 + 2 * t);
      a0 += wn * bf2f((unsigned short)(pv & 0xFFFFu));
      a1 += wn * bf2f((unsigned short)(pv >> 16));
    }
  }
  float2 mv = *(const float2*)(mem + (size_t)m * 512 + 2 * t);
  a0 += mv.x;
  a1 += mv.y;
  float ss = a0 * a0 + a1 * a1;
  #pragma unroll
  for (int k = 1; k < 64; k <<= 1) ss += __shfl_xor(ss, k);
  __syncthreads();
  if ((t & 63) == 0) red[t >> 6] = ss;
  __syncthreads();
  float tot = red[0] + red[1] + red[2] + red[3];
  float rn = 1.0f / fmaxf(sqrtf(tot), 1e-12f);
  unsigned short b0 = f2bf(a0 * rn), b1 = f2bf(a1 * rn);
  *(unsigned*)(mu + ((size_t)br * 1024 + m) * 512 + 2 * t) = (unsigned)b0 | ((unsigned)b1 << 16);
  muT[(size_t)(br * 512 + 2 * t) * 1024 + m] = b0;
  muT[(size_t)(br * 512 + 2 * t + 1) * 1024 + m] = b1;
}

extern "C" void kernel_launch(void* const* d_in, const int* in_sizes, int n_in,
                              void* d_out, int out_size, void* d_ws, size_t ws_size,
                              hipStream_t stream) {
  const float* feat = (const float*)d_in[0];
  const float* memR = (const float*)d_in[2];
  const float* memF = (const float*)d_in[3];
  float* out = (float*)d_out;
  char* ws = (char*)d_ws;

  size_t off = 0;
  auto alloc = [&](size_t bytes) {
    void* p = ws + off;
    off += (bytes + 255) & ~(size_t)255;
    return p;
  };
  unsigned short* qf = (unsigned short*)alloc(33554432);    // [32768,512] bf16
  unsigned short* E = (unsigned short*)alloc(134217728);    // [32768,2048] bf16
  unsigned long long* rowPackAll = (unsigned long long*)alloc(524288);  // zero start
  unsigned* colMaxAll = (unsigned*)alloc(8192);
  float* rowsumAll = (float*)alloc(262144);
  int* count = (int*)alloc(8192);
  int* cursor = (int*)alloc(8192);                          // zero end
  size_t zero_bytes = ((char*)cursor + 8192) - (char*)rowPackAll;
  int* start = (int*)alloc(8192);
  float* wArr = (float*)alloc(262144);
  int* colArr = (int*)alloc(262144);
  int* idxArr = (int*)alloc(262144);
  unsigned short* mu = (unsigned short*)alloc(2097152);     // [2048,512] bf16
  unsigned short* muT = (unsigned short*)alloc(2097152);    // [1024,1024] bf16
  unsigned short* memB = (unsigned short*)alloc(2097152);   // [2048,512] bf16
  if (off > ws_size) return;  // workspace too small: fail validation cleanly

  hipMemsetAsync(rowPackAll, 0, zero_bytes, stream);
  kcvt2<<<4096, 256, 0, stream>>>(memR, memF, memB);
  kqf2<<<512, 256, 0, stream>>>(feat, (unsigned*)qf, out);

  // score pass (both branches): M=2048, K=512, GX=16
  gemmM<0, 4><<<4096, 256, 0, stream>>>(qf, memB, 512, 512, 512,
                                        rowPackAll, colMaxAll, nullptr, nullptr, nullptr);
  kwcol<<<dim3(128, 2), 256, 0, stream>>>(rowPackAll, colMaxAll, wArr, colArr, count);
  kprefix<<<2, 1024, 0, stream>>>(count, start, cursor);
  kfill<<<dim3(128, 2), 256, 0, stream>>>(colArr, cursor, idxArr);
  kgathermem<<<dim3(1024, 2), 256, 0, stream>>>(qf, wArr, idxArr, start, count,
                                                memR, memF, mu, muT);
  // read pass (both branches): M=2048, K=512, GX=16
  gemmM<1, 4><<<4096, 256, 0, stream>>>(qf, mu, 512, 512, 512,
                                        nullptr, nullptr, E, rowsumAll, nullptr);
  // PV pass (both branches): M=1024, K=1024, GX=8
  gemmM<2, 3><<<2048, 256, 0, stream>>>(E, muT, 1024, 2048, 1024,
                                        nullptr, nullptr, nullptr, rowsumAll, out);
}

// Round 6
// 461.768 us; speedup vs baseline: 3.1233x; 1.1426x over previous
//
#include <hip/hip_runtime.h>
#include <stdint.h>

typedef __attribute__((ext_vector_type(8))) short bf16x8;
typedef __attribute__((ext_vector_type(4))) float f32x4;

__device__ __forceinline__ unsigned short f2bf(float f) {
  unsigned u = __float_as_uint(f);
  u += 0x7FFFu + ((u >> 16) & 1u);
  return (unsigned short)(u >> 16);
}
__device__ __forceinline__ float bf2f(unsigned short b) {
  return __uint_as_float(((unsigned)b) << 16);
}
// monotone float->u32 transform (order-preserving), and inverse
__device__ __forceinline__ unsigned xform(float s) {
  unsigned u = __float_as_uint(s);
  return (u & 0x80000000u) ? ~u : (u | 0x80000000u);
}
__device__ __forceinline__ float inv_xform(unsigned t) {
  unsigned u = (t & 0x80000000u) ? (t & 0x7FFFFFFFu) : ~t;
  return __uint_as_float(u);
}

__device__ __forceinline__ void gl_lds16(const void* g, void* l) {
  __builtin_amdgcn_global_load_lds(
      (const __attribute__((address_space(1))) unsigned*)g,
      (__attribute__((address_space(3))) unsigned*)l, 16, 0, 0);
}

// ---------------- both mems fp32 -> bf16 into concat buffer [2048,512] -------
__global__ void kcvt2(const float* __restrict__ memR, const float* __restrict__ memF,
                      unsigned short* __restrict__ memB) {
  int i = blockIdx.x * 256 + threadIdx.x;  // 0..1048575
  const float* src = (i < 524288) ? memR : memF;
  memB[i] = f2bf(src[i & 524287]);
}

// ------- fused: per-pixel l2norm + q fp32 out (both regions) + qf bf16 -------
// q = feat/||feat|| (mask scaling is uniform over channels, cancels in l2norm)
// qf written via XOR-swizzled LDS transpose -> fully coalesced global stores.
__global__ __launch_bounds__(256) void kqf2(const float* __restrict__ feat,
                                            unsigned* __restrict__ qf32,
                                            float* __restrict__ out) {
  __shared__ unsigned buf[32 * 256];  // 32 KiB
  __shared__ float red[4][64];
  int n0 = blockIdx.x * 64;
  int lane = threadIdx.x & 63, wv = threadIdx.x >> 6;
  int b = n0 >> 12, hw0 = n0 & 4095;
  const float* fp = feat + (size_t)b * (512 * 4096) + (size_t)(wv * 128) * 4096 + hw0 + lane;
  unsigned pk[64];
  float ss = 0.f;
  #pragma unroll
  for (int i = 0; i < 64; ++i) {
    float v0 = fp[(size_t)(2 * i) * 4096];
    float v1 = fp[(size_t)(2 * i + 1) * 4096];
    ss += v0 * v0 + v1 * v1;
    pk[i] = (unsigned)f2bf(v0) | ((unsigned)f2bf(v1) << 16);
  }
  red[wv][lane] = ss;
  __syncthreads();
  float tot = red[0][lane] + red[1][lane] + red[2][lane] + red[3][lane];
  float rn = 1.0f / fmaxf(sqrtf(tot), 1e-12f);
  float* ob = out + ((size_t)b * 2048 + wv * 128) * 4096 + hw0 + lane;
  #pragma unroll
  for (int i = 0; i < 64; ++i) {
    float q0 = bf2f((unsigned short)(pk[i] & 0xFFFFu)) * rn;
    float q1 = bf2f((unsigned short)(pk[i] >> 16)) * rn;
    ob[(size_t)(2 * i) * 4096] = q0;
    ob[(size_t)(2 * i) * 4096 + (size_t)1024 * 4096] = q0;
    ob[(size_t)(2 * i + 1) * 4096] = q1;
    ob[(size_t)(2 * i + 1) * 4096 + (size_t)1024 * 4096] = q1;
    pk[i] = (unsigned)f2bf(q0) | ((unsigned)f2bf(q1) << 16);
  }
  // two transpose passes (32 pixel-rows each) through XOR-swizzled LDS
  #pragma unroll
  for (int p = 0; p < 2; ++p) {
    __syncthreads();
    if ((lane >> 5) == p) {
      int px = lane & 31;
      #pragma unroll
      for (int i = 0; i < 64; ++i) buf[px * 256 + ((wv * 64 + i) ^ px)] = pk[i];
    }
    __syncthreads();
    #pragma unroll
    for (int r = 0; r < 32; ++r) {
      int row = p * 32 + r;
      qf32[(size_t)(n0 + row) * 256 + threadIdx.x] = buf[r * 256 + (threadIdx.x ^ r)];
    }
  }
}

// -------- merged GEMM (A[*,K] x B[*,K]^T), 128x128 tile, fused epilogues ----
// Both branches in one dispatch (B is branch-concat along rows / M dim).
// 1D grid with bijective XCD swizzle (blocks sharing an A-panel stay on one XCD).
// T2 LDS swizzle, global_load_lds-compatible: LDS dest stays LINEAR; the
// per-lane GLOBAL source column slot is pre-permuted (slot ^= row&7), and the
// fragment ds_read applies the same XOR -> 16-way bank conflict becomes 2-way
// (free, m136).
// MODE 0: score pass  -> rowPackAll (u64 max) + colMaxAll (u32 max); br = m0>>10
// MODE 1: read pass   -> E[n, 2048] = exp(score2) bf16 + rowsumAll atomics
// MODE 2: PV pass     -> out = (E_br @ muT)/rowsum, fp32 transposed store; br = m0>>9
template <int MODE, int LGX>
__global__ __launch_bounds__(256) void gemmM(
    const unsigned short* __restrict__ A, const unsigned short* __restrict__ B,
    int K, int lda, int ldb,
    unsigned long long* __restrict__ rowPackAll, unsigned* __restrict__ colMaxAll,
    unsigned short* __restrict__ Eout, float* __restrict__ rowsumAll,
    float* __restrict__ out) {
  __shared__ __align__(16) unsigned char smraw[33792];
  unsigned short* As = (unsigned short*)smraw;
  unsigned short* Bs = As + 8192;
  const int bid = blockIdx.x;
  const int xcd = bid & 7;
  const int tt0 = bid >> 3;
  const int m0 = (tt0 & ((1 << LGX) - 1)) * 128;
  const int n0 = (xcd + (tt0 >> LGX) * 8) * 128;
  const int tid = threadIdx.x;
  const int wid = tid >> 6, lane = tid & 63;
  const int wr = wid >> 1, wc = wid & 1;
  const int lr = lane & 15, lg = lane >> 4;
  const int srow = lane >> 3;
  const int scol = ((lane & 7) ^ srow) * 8;  // T2: pre-swizzled source slot
  const size_t brOffA = (MODE == 2) ? (size_t)((m0 >> 9) * 1024) : 0;

  f32x4 acc[4][4];
  #pragma unroll
  for (int i = 0; i < 4; ++i)
    #pragma unroll
    for (int j = 0; j < 4; ++j) acc[i][j] = (f32x4){0.f, 0.f, 0.f, 0.f};

  for (int k0 = 0; k0 < K; k0 += 64) {
    __syncthreads();
    #pragma unroll
    for (int i = 0; i < 4; ++i) {
      int ci = wid * 4 + i;
      int row = ci * 8 + srow;
      gl_lds16(A + brOffA + (size_t)(n0 + row) * lda + k0 + scol, As + ci * 512);
      gl_lds16(B + (size_t)(m0 + row) * ldb + k0 + scol, Bs + ci * 512);
    }
    __syncthreads();
    #pragma unroll
    for (int kk = 0; kk < 64; kk += 32) {
      bf16x8 af[4], bfr[4];
      #pragma unroll
      for (int f = 0; f < 4; ++f)
        af[f] = *(const bf16x8*)&As[(wr * 64 + f * 16 + lr) * 64 +
                                    ((((kk >> 3) + lg) ^ (lr & 7)) * 8)];
      #pragma unroll
      for (int f = 0; f < 4; ++f)
        bfr[f] = *(const bf16x8*)&Bs[(wc * 64 + f * 16 + lr) * 64 +
                                     ((((kk >> 3) + lg) ^ (lr & 7)) * 8)];
      #pragma unroll
      for (int fi = 0; fi < 4; ++fi)
        #pragma unroll
        for (int fj = 0; fj < 4; ++fj)
          acc[fi][fj] = __builtin_amdgcn_mfma_f32_16x16x32_bf16(af[fi], bfr[fj], acc[fi][fj], 0, 0, 0);
    }
  }
  // D frag mapping (verified m89): col = lr (+fj*16), row = lg*4+r (+fi*16)

  if constexpr (MODE == 0) {
    const int br = m0 >> 10;
    #pragma unroll
    for (int fi = 0; fi < 4; ++fi) {
      #pragma unroll
      for (int r = 0; r < 4; ++r) {
        float best = acc[fi][0][r];
        int bj = 0;
        #pragma unroll
        for (int fj = 1; fj < 4; ++fj) {
          float v = acc[fi][fj][r];
          if (v > best) { best = v; bj = fj; }
        }
        int slot = (m0 + wc * 64 + bj * 16 + lr) & 1023;
        unsigned long long pk =
            ((unsigned long long)xform(best) << 32) | (unsigned)(0xFFFFFFFFu - (unsigned)slot);
        #pragma unroll
        for (int msk = 1; msk < 16; msk <<= 1) {
          unsigned long long o = __shfl_xor(pk, msk);
          if (o > pk) pk = o;
        }
        if (lr == 0)
          atomicMax(&rowPackAll[(size_t)br * 32768 + n0 + wr * 64 + fi * 16 + lg * 4 + r], pk);
      }
    }
    #pragma unroll
    for (int fj = 0; fj < 4; ++fj) {
      float cm = acc[0][fj][0];
      #pragma unroll
      for (int fi = 0; fi < 4; ++fi)
        #pragma unroll
        for (int r = 0; r < 4; ++r) cm = fmaxf(cm, acc[fi][fj][r]);
      cm = fmaxf(cm, __shfl_xor(cm, 16));
      cm = fmaxf(cm, __shfl_xor(cm, 32));
      if (lg == 0) atomicMax(&colMaxAll[m0 + wc * 64 + fj * 16 + lr], xform(cm));
    }
  }

  if constexpr (MODE == 1) {
    const int br = m0 >> 10;
    __syncthreads();
    unsigned short(*bt)[130] = (unsigned short(*)[130])smraw;
    #pragma unroll
    for (int fi = 0; fi < 4; ++fi) {
      #pragma unroll
      for (int r = 0; r < 4; ++r) {
        int rowl = wr * 64 + fi * 16 + lg * 4 + r;
        float p = 0.f;
        #pragma unroll
        for (int fj = 0; fj < 4; ++fj) {
          float e = __expf(acc[fi][fj][r]);
          p += e;
          bt[rowl][wc * 64 + fj * 16 + lr] = f2bf(e);
        }
        #pragma unroll
        for (int msk = 1; msk < 16; msk <<= 1) p += __shfl_xor(p, msk);
        if (lr == 0) atomicAdd(&rowsumAll[(size_t)br * 32768 + n0 + rowl], p);
      }
    }
    __syncthreads();
    int row = tid >> 1, half = tid & 1;
    unsigned short* dst = Eout + (size_t)(n0 + row) * 2048 + m0 + half * 64;
    const unsigned* su = (const unsigned*)(bt[row] + half * 64);
    #pragma unroll
    for (int i = 0; i < 8; ++i) {
      uint4 q4 = make_uint4(su[i * 4 + 0], su[i * 4 + 1], su[i * 4 + 2], su[i * 4 + 3]);
      *(uint4*)(dst + i * 8) = q4;
    }
  }

  if constexpr (MODE == 2) {
    const int br = m0 >> 9;
    const int m0l = m0 & 511;
    float(*bt32)[132] = (float(*)[132])smraw;
    const int b = n0 >> 12, hw0 = n0 & 4095;
    const float* rs = rowsumAll + (size_t)br * 32768;
    #pragma unroll
    for (int h = 0; h < 2; ++h) {
      __syncthreads();
      if (wc == h) {
        #pragma unroll
        for (int fi = 0; fi < 4; ++fi) {
          #pragma unroll
          for (int r = 0; r < 4; ++r) {
            int rowl = wr * 64 + fi * 16 + lg * 4 + r;
            float inv = 1.0f / rs[n0 + rowl];
            #pragma unroll
            for (int fj = 0; fj < 4; ++fj)
              bt32[fj * 16 + lr][rowl] = acc[fi][fj][r] * inv;
          }
        }
      }
      __syncthreads();
      float* ob = out + ((size_t)b * 2048 + 512 + br * 1024 + m0l + h * 64) * 4096 + hw0;
      #pragma unroll
      for (int t8 = 0; t8 < 8; ++t8) {
        int idx = t8 * 256 + tid;
        int row = idx >> 5;        // channel within this 64-half
        int off = (idx & 31) * 4;  // pixel offset, float4
        *(float4*)&ob[(size_t)row * 4096 + off] = *(const float4*)&bt32[row][off];
      }
    }
  }
}

// ---------------- w/col unpack + slot histogram (both branches) --------------
__global__ void kwcol(const unsigned long long* __restrict__ rowPackAll,
                      const unsigned* __restrict__ colMaxAll,
                      float* __restrict__ wArr, int* __restrict__ colArr,
                      int* __restrict__ count) {
  int br = blockIdx.y;
  int n = blockIdx.x * 256 + threadIdx.x;
  unsigned long long pk = rowPackAll[(size_t)br * 32768 + n];
  float smax = inv_xform((unsigned)(pk >> 32));
  int slot = (int)(0xFFFFFFFFu - (unsigned)(pk & 0xFFFFFFFFu));
  wArr[(size_t)br * 32768 + n] = __expf(smax - inv_xform(colMaxAll[br * 1024 + slot]));
  colArr[(size_t)br * 32768 + n] = slot;
  atomicAdd(&count[br * 1024 + slot], 1);
}

// ---------------- exclusive prefix over 1024 counts (per branch) -------------
__global__ void kprefix(const int* __restrict__ count, int* __restrict__ start,
                        int* __restrict__ cursor) {
  __shared__ int sm[1024];
  int br = blockIdx.x;
  int t = threadIdx.x;
  int v = count[br * 1024 + t];
  sm[t] = v;
  __syncthreads();
  int acc = v;
  #pragma unroll
  for (int off = 1; off < 1024; off <<= 1) {
    int o = (t >= off) ? sm[t - off] : 0;
    __syncthreads();
    acc += o;
    sm[t] = acc;
    __syncthreads();
  }
  int ex = acc - v;  // exclusive prefix (branch-local)
  start[br * 1024 + t] = ex;
  cursor[br * 1024 + t] = ex;
}

// ---------------- bucket query indices by slot (both branches) ---------------
__global__ void kfill(const int* __restrict__ colArr, int* __restrict__ cursor,
                      int* __restrict__ idxArr) {
  int br = blockIdx.y;
  int n = blockIdx.x * 256 + threadIdx.x;
  int pos = atomicAdd(&cursor[br * 1024 + colArr[(size_t)br * 32768 + n]], 1);
  idxArr[(size_t)br * 32768 + pos] = n;
}

// ------- gather segment-sum + mem add + l2norm -> mu (concat) + muT (concat) -
__global__ __launch_bounds__(256) void kgathermem(
    const unsigned short* __restrict__ qf, const float* __restrict__ wArr,
    const int* __restrict__ idxArr, const int* __restrict__ start,
    const int* __restrict__ count, const float* __restrict__ memR,
    const float* __restrict__ memF,
    unsigned short* __restrict__ mu, unsigned short* __restrict__ muT) {
  __shared__ int sidx[1024];
  __shared__ float sw[1024];
  __shared__ float red[4];
  int m = blockIdx.x, br = blockIdx.y, t = threadIdx.x;
  int s = start[br * 1024 + m], cnt = count[br * 1024 + m];
  const int* idx = idxArr + (size_t)br * 32768;
  const float* w = wArr + (size_t)br * 32768;
  const float* mem = br ? memF : memR;
  float a0 = 0.f, a1 = 0.f;
  for (int base = 0; base < cnt; base += 1024) {
    int lim = min(cnt - base, 1024);
    __syncthreads();
    for (int e = t; e < lim; e += 256) {
      int n = idx[s + base + e];
      sidx[e] = n;
      sw[e] = w[n];
    }
    __syncthreads();
    for (int e = 0; e < lim; ++e) {
      int n = sidx[e];
      float wn = sw[e];
      unsigned pv = *(const unsigned*)(qf + (size_t)n * 512 + 2 * t);
      a0 += wn * bf2f((unsigned short)(pv & 0xFFFFu));
      a1 += wn * bf2f((unsigned short)(pv >> 16));
    }
  }
  float2 mv = *(const float2*)(mem + (size_t)m * 512 + 2 * t);
  a0 += mv.x;
  a1 += mv.y;
  float ss = a0 * a0 + a1 * a1;
  #pragma unroll
  for (int k = 1; k < 64; k <<= 1) ss += __shfl_xor(ss, k);
  __syncthreads();
  if ((t & 63) == 0) red[t >> 6] = ss;
  __syncthreads();
  float tot = red[0] + red[1] + red[2] + red[3];
  float rn = 1.0f / fmaxf(sqrtf(tot), 1e-12f);
  unsigned short b0 = f2bf(a0 * rn), b1 = f2bf(a1 * rn);
  *(unsigned*)(mu + ((size_t)br * 1024 + m) * 512 + 2 * t) = (unsigned)b0 | ((unsigned)b1 << 16);
  muT[(size_t)(br * 512 + 2 * t) * 1024 + m] = b0;
  muT[(size_t)(br * 512 + 2 * t + 1) * 1024 + m] = b1;
}

extern "C" void kernel_launch(void* const* d_in, const int* in_sizes, int n_in,
                              void* d_out, int out_size, void* d_ws, size_t ws_size,
                              hipStream_t stream) {
  const float* feat = (const float*)d_in[0];
  const float* memR = (const float*)d_in[2];
  const float* memF = (const float*)d_in[3];
  float* out = (float*)d_out;
  char* ws = (char*)d_ws;

  size_t off = 0;
  auto alloc = [&](size_t bytes) {
    void* p = ws + off;
    off += (bytes + 255) & ~(size_t)255;
    return p;
  };
  unsigned short* qf = (unsigned short*)alloc(33554432);    // [32768,512] bf16
  unsigned short* E = (unsigned short*)alloc(134217728);    // [32768,2048] bf16
  unsigned long long* rowPackAll = (unsigned long long*)alloc(524288);  // zero start
  unsigned* colMaxAll = (unsigned*)alloc(8192);
  float* rowsumAll = (float*)alloc(262144);
  int* count = (int*)alloc(8192);
  int* cursor = (int*)alloc(8192);                          // zero end
  size_t zero_bytes = ((char*)cursor + 8192) - (char*)rowPackAll;
  int* start = (int*)alloc(8192);
  float* wArr = (float*)alloc(262144);
  int* colArr = (int*)alloc(262144);
  int* idxArr = (int*)alloc(262144);
  unsigned short* mu = (unsigned short*)alloc(2097152);     // [2048,512] bf16
  unsigned short* muT = (unsigned short*)alloc(2097152);    // [1024,1024] bf16
  unsigned short* memB = (unsigned short*)alloc(2097152);   // [2048,512] bf16
  if (off > ws_size) return;  // workspace too small: fail validation cleanly

  hipMemsetAsync(rowPackAll, 0, zero_bytes, stream);
  kcvt2<<<4096, 256, 0, stream>>>(memR, memF, memB);
  kqf2<<<512, 256, 0, stream>>>(feat, (unsigned*)qf, out);

  // score pass (both branches): M=2048, K=512, GX=16
  gemmM<0, 4><<<4096, 256, 0, stream>>>(qf, memB, 512, 512, 512,
                                        rowPackAll, colMaxAll, nullptr, nullptr, nullptr);
  kwcol<<<dim3(128, 2), 256, 0, stream>>>(rowPackAll, colMaxAll, wArr, colArr, count);
  kprefix<<<2, 1024, 0, stream>>>(count, start, cursor);
  kfill<<<dim3(128, 2), 256, 0, stream>>>(colArr, cursor, idxArr);
  kgathermem<<<dim3(1024, 2), 256, 0, stream>>>(qf, wArr, idxArr, start, count,
                                                memR, memF, mu, muT);
  // read pass (both branches): M=2048, K=512, GX=16
  gemmM<1, 4><<<4096, 256, 0, stream>>>(qf, mu, 512, 512, 512,
                                        nullptr, nullptr, E, rowsumAll, nullptr);
  // PV pass (both branches): M=1024, K=1024, GX=8
  gemmM<2, 3><<<2048, 256, 0, stream>>>(E, muT, 1024, 2048, 1024,
                                        nullptr, nullptr, nullptr, rowsumAll, out);
}